// Round 14
// baseline (321.011 us; speedup 1.0000x reference)
//
#include <hip/hip_runtime.h>
#include <hip/hip_bf16.h>
#include <stdint.h>

using f32x4   = __attribute__((ext_vector_type(4))) float;
using half8   = __attribute__((ext_vector_type(8))) _Float16;
using half4   = __attribute__((ext_vector_type(4))) _Float16;
using half2v  = __attribute__((ext_vector_type(2))) _Float16;
using float4v = __attribute__((ext_vector_type(4))) float;

typedef const __attribute__((address_space(1))) void gas_void;
typedef __attribute__((address_space(3))) void las_void;

__device__ __forceinline__ void gload_lds16(const void* gptr, void* lptr) {
  __builtin_amdgcn_global_load_lds((gas_void*)(uintptr_t)gptr,
                                   (las_void*)(uintptr_t)lptr, 16, 0, 0);
}

#define MFMA_F16(a, b, c) __builtin_amdgcn_mfma_f32_16x16x32_f16((a), (b), (c), 0, 0, 0)

// ---------- x fp32 -> x16 [50176][768] AND xT [16][768][3136]; tail blocks do weights ----------
__global__ __launch_bounds__(256)
void k_cvtx(const float* __restrict__ x, _Float16* __restrict__ x16,
            _Float16* __restrict__ xT,
            const float* __restrict__ wqkv, const float* __restrict__ wproj,
            _Float16* __restrict__ w16, _Float16* __restrict__ wp16,
            _Float16* __restrict__ wvT) {
  const int bid = blockIdx.x;
  if (bid >= 9408) {
    const long N1 = 221184L, N2 = 73728L, N3 = 98304L;  // 8-elem units
    const long total = N1 + N2 + N3;
    for (long i = (long)(bid - 9408) * blockDim.x + threadIdx.x; i < total;
         i += 512L * blockDim.x) {
      if (i < N1 + N2) {
        const float* src; _Float16* dst; long off;
        if (i < N1) { src = wqkv;  dst = w16;  off = i; }
        else        { src = wproj; dst = wp16; off = i - N1; }
        const float4v* p = (const float4v*)(src + off * 8);
        float4v a = p[0], b = p[1];
        half8 o;
        o[0] = (_Float16)a[0]; o[1] = (_Float16)a[1]; o[2] = (_Float16)a[2]; o[3] = (_Float16)a[3];
        o[4] = (_Float16)b[0]; o[5] = (_Float16)b[1]; o[6] = (_Float16)b[2]; o[7] = (_Float16)b[3];
        *(half8*)(dst + off * 8) = o;
      } else {
        const long u = i - N1 - N2;
        const int h = (int)(u / 6144);
        const int r = (int)(u % 6144);
        const int f = r >> 3, e0 = (r & 7) * 8;
        half8 o;
        if (e0 >= 48) {
#pragma unroll
          for (int j = 0; j < 8; ++j) o[j] = (_Float16)0.f;
        } else {
#pragma unroll
          for (int j = 0; j < 8; ++j)
            o[j] = (_Float16)wqkv[(long)(1536 + h * 48 + e0 + j) * 768 + f];
        }
        *(half8*)(wvT + ((long)(h * 768 + f) * 64 + e0)) = o;
      }
    }
    return;
  }
  __shared__ _Float16 lt[64 * 66];
  const int b = bid / 588;
  const int rem = bid % 588;
  const int tt = rem / 12, ct = rem % 12;
  const long t0g = (long)b * 3136 + tt * 64;
  const int c0 = ct * 64;
  const int tid = threadIdx.x;
#pragma unroll
  for (int ch = 0; ch < 4; ++ch) {
    const int idx = tid + ch * 256;
    const int tr = idx >> 4, cg = (idx & 15) * 4;
    float4v v = *(const float4v*)&x[(t0g + tr) * 768 + c0 + cg];
    half4 hv;
    hv[0] = (_Float16)v[0]; hv[1] = (_Float16)v[1];
    hv[2] = (_Float16)v[2]; hv[3] = (_Float16)v[3];
    *(half4*)&x16[(t0g + tr) * 768 + c0 + cg] = hv;
    half2v lo, hi;
    lo[0] = hv[0]; lo[1] = hv[1]; hi[0] = hv[2]; hi[1] = hv[3];
    *(half2v*)&lt[tr * 66 + cg]     = lo;
    *(half2v*)&lt[tr * 66 + cg + 2] = hi;
  }
  __syncthreads();
  const int c = tid >> 2, tch = tid & 3;
  half8 o0, o1;
#pragma unroll
  for (int j = 0; j < 8; ++j) o0[j] = lt[(tch * 16 + j) * 66 + c];
#pragma unroll
  for (int j = 0; j < 8; ++j) o1[j] = lt[(tch * 16 + 8 + j) * 66 + c];
  _Float16* dst = xT + (long)b * 2408448 + (long)(c0 + c) * 3136 + tt * 64 + tch * 16;
  *(half8*)dst = o0;
  *(half8*)(dst + 8) = o1;
}

// ==================== Gram: G_b = xT_b . xT_b^T, symmetric 128^2 tiles ====================
__global__ __launch_bounds__(512)
void k_gram(const _Float16* __restrict__ xT, _Float16* __restrict__ G) {
  __shared__ _Float16 lds[2][2][128 * 64];   // 64 KiB
  const int tid = threadIdx.x;
  const int wv = tid >> 6, lane = tid & 63;
  const int g = lane >> 4, cidx = lane & 15;
  const int wr = wv >> 2, wc = wv & 3;

  const int nwg = (int)gridDim.x;
  const int q = nwg >> 3, r = nwg & 7;
  const int xcd = (int)blockIdx.x & 7, bidx = (int)blockIdx.x >> 3;
  int wg = (xcd < r ? xcd * (q + 1) : r * (q + 1) + (xcd - r) * q) + bidx;
  const int b = wg / 21;
  int p = wg % 21;
  int mt = 0;
  while (p >= 6 - mt) { p -= 6 - mt; ++mt; }
  const int nt = mt + p;

  const _Float16* Ab = xT + (long)b * 2408448 + (long)mt * 128 * 3136;
  const _Float16* Bb = xT + (long)b * 2408448 + (long)nt * 128 * 3136;

  const int srow8 = lane >> 3;
  const int sgr8  = (lane & 7) ^ srow8;

  auto stage = [&](int buf, int kt) {
#pragma unroll
    for (int l = 0; l < 2; ++l) {
      const int chunk = l * 8 + wv;
      const long grow = chunk * 8 + srow8;
      const long koff = (long)kt * 64 + sgr8 * 8;
      gload_lds16(Ab + grow * 3136 + koff, &lds[buf][0][chunk * 512]);
      gload_lds16(Bb + grow * 3136 + koff, &lds[buf][1][chunk * 512]);
    }
  };

  f32x4 acc[4][2] = {};
  stage(0, 0);
  __syncthreads();
  for (int kt = 0; kt < 49; ++kt) {
    const int cur = kt & 1;
    if (kt + 1 < 49) stage(cur ^ 1, kt + 1);
    half8 af[4][2], bf[2][2];
#pragma unroll
    for (int ks = 0; ks < 2; ++ks) {
      const int gran = (((ks << 2) + g) ^ (cidx & 7)) * 8;
#pragma unroll
      for (int m = 0; m < 4; ++m)
        af[m][ks] = *(const half8*)&lds[cur][0][(wr * 64 + m * 16 + cidx) * 64 + gran];
#pragma unroll
      for (int n = 0; n < 2; ++n)
        bf[n][ks] = *(const half8*)&lds[cur][1][(wc * 32 + n * 16 + cidx) * 64 + gran];
    }
#pragma unroll
    for (int ks = 0; ks < 2; ++ks)
#pragma unroll
      for (int m = 0; m < 4; ++m)
#pragma unroll
        for (int n = 0; n < 2; ++n)
          acc[m][n] = MFMA_F16(af[m][ks], bf[n][ks], acc[m][n]);
    __syncthreads();
  }
  _Float16* Gb = G + (long)b * 589824;
  const long m0 = (long)mt * 128, n0 = (long)nt * 128;
#pragma unroll
  for (int m = 0; m < 4; ++m)
#pragma unroll
    for (int rr = 0; rr < 4; ++rr) {
      const long row = m0 + wr * 64 + m * 16 + g * 4 + rr;
#pragma unroll
      for (int n = 0; n < 2; ++n)
        Gb[row * 768 + n0 + wc * 32 + n * 16 + cidx] = (_Float16)acc[m][n][rr];
    }
  if (mt != nt) {
#pragma unroll
    for (int m = 0; m < 4; ++m)
#pragma unroll
      for (int n = 0; n < 2; ++n) {
        half4 hv;
#pragma unroll
        for (int rr = 0; rr < 4; ++rr) hv[rr] = (_Float16)acc[m][n][rr];
        const long col  = n0 + wc * 32 + n * 16 + cidx;
        const long row0 = m0 + wr * 64 + m * 16 + g * 4;
        *(half4*)&Gb[col * 768 + row0] = hv;
      }
  }
}

#define XPH(CURA, CURB, MLO, NA, NBUF, NKS, NMLO, LOADB, NB, STAGE, BDRY)      \
  {                                                                            \
    STAGE;                                                                     \
    if (BDRY) {                                                                \
      asm volatile("s_waitcnt vmcnt(4)" ::: "memory");                         \
      __builtin_amdgcn_sched_barrier(0);                                       \
    }                                                                          \
    __builtin_amdgcn_s_barrier();                                              \
    _Pragma("unroll")                                                          \
    for (int mm = 0; mm < 4; ++mm)                                             \
      NA[mm] = *(const half8*)&lds[(NBUF)*32768 + (NKS)*8192 + raA + ((NMLO)+mm)*512]; \
    if (LOADB) {                                                               \
      _Pragma("unroll")                                                        \
      for (int nn = 0; nn < 4; ++nn)                                           \
        NB[nn] = *(const half8*)&lds[(NBUF)*32768 + (NKS)*8192 + raB + nn*512]; \
    }                                                                          \
    __builtin_amdgcn_sched_barrier(0);                                         \
    __builtin_amdgcn_s_setprio(1);                                             \
    _Pragma("unroll")                                                          \
    for (int mm = 0; mm < 4; ++mm)                                             \
      _Pragma("unroll")                                                        \
      for (int nn = 0; nn < 4; ++nn)                                           \
        acc[(MLO)+mm][nn] = MFMA_F16(CURA[mm], CURB[nn], acc[(MLO)+mm][nn]);   \
    __builtin_amdgcn_s_setprio(0);                                             \
    __builtin_amdgcn_s_barrier();                                              \
  }

// ==================== 256x256 8-phase bt-GEMM (wfin) ====================
template<bool OUT_F32>
__global__ __launch_bounds__(512, 2)
void k_gemm8p(const _Float16* __restrict__ A, const _Float16* __restrict__ B,
              void* __restrict__ Cv, const float* __restrict__ bias,
              int Mt, int Nt, long Areal, long Astr, long Bstr, long Cstr,
              long N, long K)
{
  __shared__ _Float16 lds[65536];  // 128 KiB
  const int tid  = threadIdx.x;
  const int wv   = tid >> 6, lane = tid & 63;
  const int g    = lane >> 4, cidx = lane & 15;
  const int wr   = wv >> 2, wc = wv & 3;

  const int nwg = (int)gridDim.x;
  const int q = nwg >> 3, r = nwg & 7;
  const int xcd = (int)blockIdx.x & 7, bidx = (int)blockIdx.x >> 3;
  int wg = (xcd < r ? xcd * (q + 1) : r * (q + 1) + (xcd - r) * q) + bidx;

  const int tpb = Mt * Nt;
  const int b   = wg / tpb;
  const int rem = wg - b * tpb;
  const long mt = rem % Mt, nt = rem / Mt;
  const long m0 = mt * 256, n0 = nt * 256;

  const int NT = (int)(K >> 6);
  const int NI = NT >> 1;

  const _Float16* Ab = A + b * Astr + m0 * K;
  const _Float16* Bb = B + b * Bstr + n0 * K;

  const int srow = lane >> 2;
  const int sgr  = (lane & 3) ^ ((lane >> 3) & 3);

  auto stage = [&](int op, int buf, int kh, int t) {
    const _Float16* src = op ? Bb : Ab;
    const long koff = (long)t * 64 + kh * 32 + sgr * 8;
#pragma unroll
    for (int l = 0; l < 2; ++l) {
      const int chunk = l * 8 + wv;
      gload_lds16(src + (long)(chunk * 16 + srow) * K + koff,
                  &lds[buf * 32768 + op * 16384 + kh * 8192 + chunk * 512]);
    }
  };

  const int gr  = (g ^ ((cidx >> 1) & 3)) * 8;
  const int raA = (wr * 128 + cidx) * 32 + gr;
  const int raB = 16384 + (wc * 64 + cidx) * 32 + gr;

  f32x4 acc[8][4] = {};

  stage(0, 0, 0, 0); stage(1, 0, 0, 0);
  stage(0, 0, 1, 0); stage(1, 0, 1, 0);
  stage(0, 1, 0, 1); stage(1, 1, 0, 1);
  asm volatile("s_waitcnt vmcnt(4)" ::: "memory");
  __builtin_amdgcn_sched_barrier(0);
  __builtin_amdgcn_s_barrier();

  half8 afA[4], afB[4], bfA[4], bfB[4];
#pragma unroll
  for (int mm = 0; mm < 4; ++mm) afA[mm] = *(const half8*)&lds[raA + mm * 512];
#pragma unroll
  for (int nn = 0; nn < 4; ++nn) bfA[nn] = *(const half8*)&lds[raB + nn * 512];

  for (int it = 0; it < NI; ++it) {
    const int t1c = 2 * it + 1;
    int tn2 = 2 * it + 2; if (tn2 >= NT) tn2 -= NT;
    int tn3 = 2 * it + 3; if (tn3 >= NT) tn3 -= NT;
    XPH(afA, bfA, 0, afB, 0, 0, 4, 0, bfB, stage(0, 1, 1, t1c), false)
    XPH(afB, bfA, 4, afA, 0, 1, 0, 1, bfB, stage(1, 1, 1, t1c), false)
    XPH(afA, bfB, 0, afB, 0, 1, 4, 0, bfA, stage(0, 0, 0, tn2), false)
    XPH(afB, bfB, 4, afA, 1, 0, 0, 1, bfA, stage(1, 0, 0, tn2), true )
    XPH(afA, bfA, 0, afB, 1, 0, 4, 0, bfB, stage(0, 0, 1, tn2), false)
    XPH(afB, bfA, 4, afA, 1, 1, 0, 1, bfB, stage(1, 0, 1, tn2), false)
    XPH(afA, bfB, 0, afB, 1, 1, 4, 0, bfA, stage(0, 1, 0, tn3), false)
    XPH(afB, bfB, 4, afA, 0, 0, 0, 1, bfA, stage(1, 1, 0, tn3), true )
  }

  float bv[4] = {0.f, 0.f, 0.f, 0.f};
  if (bias) {
#pragma unroll
    for (int n = 0; n < 4; ++n) bv[n] = bias[n0 + wc * 64 + n * 16 + cidx];
  }
  if constexpr (OUT_F32) {
    float* C = (float*)Cv + b * Cstr;
#pragma unroll
    for (int m = 0; m < 8; ++m)
#pragma unroll
      for (int rr = 0; rr < 4; ++rr) {
        const long row = m0 + wr * 128 + m * 16 + g * 4 + rr;
        if (row < Areal) {
#pragma unroll
          for (int n = 0; n < 4; ++n)
            C[row * N + (n0 + wc * 64 + n * 16 + cidx)] = acc[m][n][rr] + bv[n];
        }
      }
  } else {
    _Float16* C = (_Float16*)Cv + b * Cstr;
#pragma unroll
    for (int m = 0; m < 8; ++m)
#pragma unroll
      for (int rr = 0; rr < 4; ++rr) {
        const long row = m0 + wr * 128 + m * 16 + g * 4 + rr;
        if (row < Areal) {
#pragma unroll
          for (int n = 0; n < 4; ++n)
            C[row * N + (n0 + wc * 64 + n * 16 + cidx)] = (_Float16)acc[m][n][rr];
        }
      }
  }
}

// ==================== k_g2t: 128x256 bt-GEMM, 3-deep A-ring / 2-deep B-ring ====================
// K=768 (12 K-tiles of 64), 8 waves (2M x 4N -> wave 64x64, acc[4][4]), 2 phases/K-tile.
// LDS 112 KiB: A 3x8192 halves @0, B 2x16384 halves @24576. Per tile t:
//  ph1: stage B(t+1)->sbn | barrier | prefetch A[sa]ks1,B[sb]ks1 | MFMA ks0 | barrier
//  ph2: stage A(t+2)->sap2 | vmcnt(2) | barrier | prefetch A[san]ks0,B[sbn]ks0 | MFMA ks1 | barrier
// Boundary vmcnt(2) forces {A(t+1),B(t+1)}, leaves A(t+2) in flight (cover > HBM lat).
// Swizzle: k_gram's 128B-row involution; ks1 = granule XOR 4 (= addr XOR 32 halves).
#define XP2(CURA, CURB, NA, NSA, NB, NSB, NKS, STAGE, BDRY)                    \
  {                                                                            \
    STAGE;                                                                     \
    if (BDRY) {                                                                \
      asm volatile("s_waitcnt vmcnt(2)" ::: "memory");                         \
      __builtin_amdgcn_sched_barrier(0);                                       \
    }                                                                          \
    __builtin_amdgcn_s_barrier();                                              \
    _Pragma("unroll")                                                          \
    for (int mm = 0; mm < 4; ++mm)                                             \
      NA[mm] = *(const half8*)&lds[(NSA)*8192 + ((raA + mm*1024) ^ ((NKS)*32))]; \
    _Pragma("unroll")                                                          \
    for (int nn = 0; nn < 4; ++nn)                                             \
      NB[nn] = *(const half8*)&lds[24576 + (NSB)*16384 + ((raB + nn*1024) ^ ((NKS)*32))]; \
    __builtin_amdgcn_sched_barrier(0);                                         \
    __builtin_amdgcn_s_setprio(1);                                             \
    _Pragma("unroll")                                                          \
    for (int mm = 0; mm < 4; ++mm)                                             \
      _Pragma("unroll")                                                        \
      for (int nn = 0; nn < 4; ++nn)                                           \
        acc[mm][nn] = MFMA_F16(CURA[mm], CURB[nn], acc[mm][nn]);               \
    __builtin_amdgcn_s_setprio(0);                                             \
    __builtin_amdgcn_s_barrier();                                              \
  }

template<bool OUT_F32>
__global__ __launch_bounds__(512, 1)
void k_g2t(const _Float16* __restrict__ A, const _Float16* __restrict__ B,
           void* __restrict__ Cv, const float* __restrict__ bias,
           int Mt, int Nt, long Areal, long Astr, long Bstr, long Cstr, long N)
{
  __shared__ _Float16 lds[57344];  // 112 KiB
  const int tid = threadIdx.x;
  const int wv = tid >> 6, lane = tid & 63;
  const int g = lane >> 4, cidx = lane & 15;
  const int wr = wv >> 2, wc = wv & 3;
  const long K = 768;

  const int nwg = (int)gridDim.x;
  const int q = nwg >> 3, r = nwg & 7;
  const int xcd = (int)blockIdx.x & 7, bidx = (int)blockIdx.x >> 3;
  int wg = (xcd < r ? xcd * (q + 1) : r * (q + 1) + (xcd - r) * q) + bidx;
  const int tpb = Mt * Nt;
  const int b = wg / tpb;
  const int rem = wg - b * tpb;
  const long mt = rem % Mt, nt = rem / Mt;   // mt-fast: share B panel
  const long m0 = mt * 128, n0 = nt * 256;

  const _Float16* Ab = A + b * Astr + m0 * K;
  const _Float16* Bb = B + b * Bstr + n0 * K;

  const int srow8 = lane >> 3;
  const int sgr8  = (lane & 7) ^ srow8;

  auto stageA = [&](int slot, int t) {   // 128 rows x 64 halves = 16 chunks, 2 loads
#pragma unroll
    for (int l = 0; l < 2; ++l) {
      const int chunk = l * 8 + wv;
      gload_lds16(Ab + (long)(chunk * 8 + srow8) * K + (long)t * 64 + sgr8 * 8,
                  &lds[slot * 8192 + chunk * 512]);
    }
  };
  auto stageB = [&](int slot, int t) {   // 256 rows = 32 chunks, 4 loads
#pragma unroll
    for (int l = 0; l < 4; ++l) {
      const int chunk = l * 8 + wv;
      gload_lds16(Bb + (long)(chunk * 8 + srow8) * K + (long)t * 64 + sgr8 * 8,
                  &lds[24576 + slot * 16384 + chunk * 512]);
    }
  };

  const int gr0 = (g ^ (cidx & 7)) * 8;
  const int raA = (wr * 64 + cidx) * 64 + gr0;   // + m*1024, ^ks*32, + slot*8192
  const int raB = (wc * 64 + cidx) * 64 + gr0;   // + n*1024, ^ks*32, + 24576 + slot*16384

  f32x4 acc[4][4] = {};

  // prologue: A(0), B(0), A(1) -> force {A0,B0}, leave A1 in flight
  stageA(0, 0);
  stageB(0, 0);
  stageA(1, 1);
  asm volatile("s_waitcnt vmcnt(2)" ::: "memory");
  __builtin_amdgcn_sched_barrier(0);
  __builtin_amdgcn_s_barrier();

  half8 afA[4], afB[4], bfA[4], bfB[4];
#pragma unroll
  for (int mm = 0; mm < 4; ++mm) afA[mm] = *(const half8*)&lds[raA + mm * 1024];
#pragma unroll
  for (int nn = 0; nn < 4; ++nn) bfA[nn] = *(const half8*)&lds[24576 + raB + nn * 1024];

  int sa = 0, sb = 0;
  for (int t = 0; t < 12; ++t) {
    const int san  = (sa == 2) ? 0 : sa + 1;
    const int sap2 = (san == 2) ? 0 : san + 1;
    const int sbn  = sb ^ 1;
    int tb1 = t + 1; if (tb1 >= 12) tb1 -= 12;
    int tb2 = t + 2; if (tb2 >= 12) tb2 -= 12;
    XP2(afA, bfA, afB, sa, bfB, sb, 1, stageB(sbn, tb1), false)
    XP2(afB, bfB, afA, san, bfA, sbn, 0, stageA(sap2, tb2), true)
    sa = san; sb = sbn;
  }

  float bv[4] = {0.f, 0.f, 0.f, 0.f};
  if (bias) {
#pragma unroll
    for (int n = 0; n < 4; ++n) bv[n] = bias[n0 + wc * 64 + n * 16 + cidx];
  }
  if constexpr (OUT_F32) {
    float* C = (float*)Cv + b * Cstr;
#pragma unroll
    for (int m = 0; m < 4; ++m)
#pragma unroll
      for (int rr = 0; rr < 4; ++rr) {
        const long row = m0 + wr * 64 + m * 16 + g * 4 + rr;
        if (row < Areal) {
#pragma unroll
          for (int n = 0; n < 4; ++n)
            C[row * N + (n0 + wc * 64 + n * 16 + cidx)] = acc[m][n][rr] + bv[n];
        }
      }
  } else {
    _Float16* C = (_Float16*)Cv + b * Cstr;
#pragma unroll
    for (int m = 0; m < 4; ++m)
#pragma unroll
      for (int rr = 0; rr < 4; ++rr) {
        const long row = m0 + wr * 64 + m * 16 + g * 4 + rr;
        if (row < Areal) {
#pragma unroll
          for (int n = 0; n < 4; ++n)
            C[row * N + (n0 + wc * 64 + n * 16 + cidx)] = (_Float16)acc[m][n][rr];
        }
      }
  }
}

// ==================== heads: S/norms from QG, softmax, WeffT. One block per (b,h) ====================
__global__ __launch_bounds__(256)
void k_heads(const _Float16* __restrict__ QG, const _Float16* __restrict__ w16,
             const _Float16* __restrict__ wvT, const float* __restrict__ temperature,
             _Float16* __restrict__ weffT)
{
  const int b = blockIdx.x >> 4, h = blockIdx.x & 15;
  const int tid = threadIdx.x;
  const int w = tid >> 6, lane = tid & 63;
  const int g = lane >> 4, c = lane & 15;

  __shared__ float red[4][48 * 48];
  __shared__ float redss[4][2][48];
  __shared__ float inv[2][48];
  __shared__ _Float16 Pb[48 * 64];

  const _Float16* QGq = QG + (long)b * 1179648 + (long)(h * 48) * 768;
  const _Float16* QGk = QGq + 768L * 768;
  const _Float16* Wq  = w16 + (long)(h * 48) * 768;
  const _Float16* Wk  = w16 + (long)(768 + h * 48) * 768;

  f32x4 aS[3][3] = {};
  f32x4 aq[3] = {};
  f32x4 ak[3] = {};
  for (int ks = w * 6; ks < w * 6 + 6; ++ks) {
    const int k0 = ks * 32 + g * 8;
    half8 t1[3], t3[3], wqf[3], wkf[3];
#pragma unroll
    for (int m = 0; m < 3; ++m) {
      const long ro = (long)(m * 16 + c) * 768 + k0;
      t1[m]  = *(const half8*)(QGq + ro);
      t3[m]  = *(const half8*)(QGk + ro);
      wqf[m] = *(const half8*)(Wq + ro);
      wkf[m] = *(const half8*)(Wk + ro);
    }
#pragma unroll
    for (int m = 0; m < 3; ++m) {
      aq[m] = MFMA_F16(t1[m], wqf[m], aq[m]);
      ak[m] = MFMA_F16(t3[m], wkf[m], ak[m]);
#pragma unroll
      for (int n = 0; n < 3; ++n)
        aS[m][n] = MFMA_F16(t1[m], wkf[n], aS[m][n]);
    }
  }

#pragma unroll
  for (int m = 0; m < 3; ++m) {
#pragma unroll
    for (int n = 0; n < 3; ++n)
#pragma unroll
      for (int rr = 0; rr < 4; ++rr)
        red[w][(m * 16 + g * 4 + rr) * 48 + n * 16 + c] = aS[m][n][rr];
#pragma unroll
    for (int rr = 0; rr < 4; ++rr)
      if (c == g * 4 + rr) {
        redss[w][0][m * 16 + c] = aq[m][rr];
        redss[w][1][m * 16 + c] = ak[m][rr];
      }
  }
  __syncthreads();

  if (tid < 96) {
    const int is_k = tid / 48, d = tid % 48;
    const float s = redss[0][is_k][d] + redss[1][is_k][d] + redss[2][is_k][d] + redss[3][is_k][d];
    inv[is_k][d] = 1.0f / fmaxf(sqrtf(s), 1e-12f);
  }
  __syncthreads();

  if (tid < 48) {
    const int d = tid;
    const float iq = inv[0][d] * temperature[h];
    float rowv[48];
    float mx = -3.0e38f;
#pragma unroll
    for (int e = 0; e < 48; ++e) {
      const int idx = d * 48 + e;
      float t = (red[0][idx] + red[1][idx] + red[2][idx] + red[3][idx]) * iq * inv[1][e];
      rowv[e] = t;
      mx = fmaxf(mx, t);
    }
    float sum = 0.f;
#pragma unroll
    for (int e = 0; e < 48; ++e) {
      const float pv = __expf(rowv[e] - mx);
      rowv[e] = pv;
      sum += pv;
    }
    const float is = 1.0f / sum;
#pragma unroll
    for (int e = 0; e < 48; ++e)
      Pb[d * 64 + e] = (_Float16)(rowv[e] * is);
#pragma unroll
    for (int e = 48; e < 64; ++e)
      Pb[d * 64 + e] = (_Float16)0.f;
  }
  __syncthreads();

  half8 pf[3][2];
#pragma unroll
  for (int nf = 0; nf < 3; ++nf)
#pragma unroll
    for (int ks = 0; ks < 2; ++ks)
      pf[nf][ks] = *(const half8*)&Pb[(nf * 16 + c) * 64 + ks * 32 + g * 8];

  const _Float16* wvh = wvT + (long)h * 768 * 64;
  _Float16* wout = weffT + (long)b * 589824 + h * 48;

  for (int m = 0; m < 12; ++m) {
    const int f0 = w * 192 + m * 16;
    half8 va[2];
#pragma unroll
    for (int ks = 0; ks < 2; ++ks)
      va[ks] = *(const half8*)&wvh[(long)(f0 + c) * 64 + ks * 32 + g * 8];
    f32x4 a3[3] = {};
#pragma unroll
    for (int ks = 0; ks < 2; ++ks)
#pragma unroll
      for (int nf = 0; nf < 3; ++nf)
        a3[nf] = MFMA_F16(va[ks], pf[nf][ks], a3[nf]);
#pragma unroll
    for (int nf = 0; nf < 3; ++nf)
#pragma unroll
      for (int rr = 0; rr < 4; ++rr)
        wout[(long)(f0 + g * 4 + rr) * 768 + nf * 16 + c] = (_Float16)a3[nf][rr];
  }
}

// -------------------- launch --------------------
extern "C" void kernel_launch(void* const* d_in, const int* in_sizes, int n_in,
                              void* d_out, int out_size, void* d_ws, size_t ws_size,
                              hipStream_t stream)
{
  (void)in_sizes; (void)n_in; (void)out_size; (void)ws_size;
  const float* x      = (const float*)d_in[0];
  const float* w_qkv  = (const float*)d_in[1];
  const float* temp   = (const float*)d_in[2];
  const float* w_proj = (const float*)d_in[3];
  const float* b_proj = (const float*)d_in[4];
  float* out = (float*)d_out;

  char* ws = (char*)d_ws;
  _Float16* x16   = (_Float16*)(ws);
  _Float16* xT    = (_Float16*)(ws + 77070336L);
  _Float16* G     = (_Float16*)(ws + 154140672L);
  _Float16* QG    = (_Float16*)(ws + 173015040L);
  _Float16* weffT = (_Float16*)(ws + 210763776L);
  _Float16* wfin  = (_Float16*)(ws + 229638144L);
  _Float16* w16   = (_Float16*)(ws + 248512512L);
  _Float16* wp16  = (_Float16*)(ws + 252051456L);
  _Float16* wvT   = (_Float16*)(ws + 253231104L);

  // x convert + transpose (blocks 0..9407) and weight converts (blocks 9408..9919)
  k_cvtx<<<9920, 256, 0, stream>>>(x, x16, xT, w_qkv, w_proj, w16, wp16, wvT);
  // G_b = xT_b . xT_b^T (symmetric), 8-wave BK=64
  k_gram<<<336, 512, 0, stream>>>(xT, G);
  // QG_b = w16[0:1536] . G_b  (128x256 deep-pipeline: 12 Mt x 3 Nt x 16 = 576 blocks)
  k_g2t<false><<<576, 512, 0, stream>>>(w16, G, QG, nullptr,
                                        12, 3, 1536, 0, 589824, 1179648, 768);
  // per (b,h): S, norms, softmax, WeffT
  k_heads<<<256, 256, 0, stream>>>(QG, w16, wvT, temp, weffT);
  // wfin_b = Wp . Weff_b  (8-phase 256^2, 144 blocks)
  k_gemm8p<false><<<144, 512, 0, stream>>>(wp16, weffT, wfin, nullptr,
                                           3, 3, 768, 0, 589824, 589824, 768, 768);
  // final: out_b = x16_b . wfin_b^T + bias  (128x256 deep-pipeline: 25 x 3 x 16 = 1200 blocks)
  k_g2t<true><<<1200, 512, 0, stream>>>(x16, wfin, out, b_proj,
                                        25, 3, 3136, 2408448, 589824, 2408448, 768);
}

// Round 15
// 314.625 us; speedup vs baseline: 1.0203x; 1.0203x over previous
//
#include <hip/hip_runtime.h>
#include <hip/hip_bf16.h>
#include <stdint.h>

using f32x4   = __attribute__((ext_vector_type(4))) float;
using half8   = __attribute__((ext_vector_type(8))) _Float16;
using half4   = __attribute__((ext_vector_type(4))) _Float16;
using half2v  = __attribute__((ext_vector_type(2))) _Float16;
using float4v = __attribute__((ext_vector_type(4))) float;

typedef const __attribute__((address_space(1))) void gas_void;
typedef __attribute__((address_space(3))) void las_void;

__device__ __forceinline__ void gload_lds16(const void* gptr, void* lptr) {
  __builtin_amdgcn_global_load_lds((gas_void*)(uintptr_t)gptr,
                                   (las_void*)(uintptr_t)lptr, 16, 0, 0);
}

#define MFMA_F16(a, b, c) __builtin_amdgcn_mfma_f32_16x16x32_f16((a), (b), (c), 0, 0, 0)

// ---------- x fp32 -> x16 [50176][768] AND xT [16][768][3136]; tail blocks do weights ----------
__global__ __launch_bounds__(256)
void k_cvtx(const float* __restrict__ x, _Float16* __restrict__ x16,
            _Float16* __restrict__ xT,
            const float* __restrict__ wqkv, const float* __restrict__ wproj,
            _Float16* __restrict__ w16, _Float16* __restrict__ wp16,
            _Float16* __restrict__ wvT) {
  const int bid = blockIdx.x;
  if (bid >= 9408) {
    const long N1 = 221184L, N2 = 73728L, N3 = 98304L;  // 8-elem units
    const long total = N1 + N2 + N3;
    for (long i = (long)(bid - 9408) * blockDim.x + threadIdx.x; i < total;
         i += 512L * blockDim.x) {
      if (i < N1 + N2) {
        const float* src; _Float16* dst; long off;
        if (i < N1) { src = wqkv;  dst = w16;  off = i; }
        else        { src = wproj; dst = wp16; off = i - N1; }
        const float4v* p = (const float4v*)(src + off * 8);
        float4v a = p[0], b = p[1];
        half8 o;
        o[0] = (_Float16)a[0]; o[1] = (_Float16)a[1]; o[2] = (_Float16)a[2]; o[3] = (_Float16)a[3];
        o[4] = (_Float16)b[0]; o[5] = (_Float16)b[1]; o[6] = (_Float16)b[2]; o[7] = (_Float16)b[3];
        *(half8*)(dst + off * 8) = o;
      } else {
        const long u = i - N1 - N2;
        const int h = (int)(u / 6144);
        const int r = (int)(u % 6144);
        const int f = r >> 3, e0 = (r & 7) * 8;
        half8 o;
        if (e0 >= 48) {
#pragma unroll
          for (int j = 0; j < 8; ++j) o[j] = (_Float16)0.f;
        } else {
#pragma unroll
          for (int j = 0; j < 8; ++j)
            o[j] = (_Float16)wqkv[(long)(1536 + h * 48 + e0 + j) * 768 + f];
        }
        *(half8*)(wvT + ((long)(h * 768 + f) * 64 + e0)) = o;
      }
    }
    return;
  }
  __shared__ _Float16 lt[64 * 66];
  const int b = bid / 588;
  const int rem = bid % 588;
  const int tt = rem / 12, ct = rem % 12;
  const long t0g = (long)b * 3136 + tt * 64;
  const int c0 = ct * 64;
  const int tid = threadIdx.x;
#pragma unroll
  for (int ch = 0; ch < 4; ++ch) {
    const int idx = tid + ch * 256;
    const int tr = idx >> 4, cg = (idx & 15) * 4;
    float4v v = *(const float4v*)&x[(t0g + tr) * 768 + c0 + cg];
    half4 hv;
    hv[0] = (_Float16)v[0]; hv[1] = (_Float16)v[1];
    hv[2] = (_Float16)v[2]; hv[3] = (_Float16)v[3];
    *(half4*)&x16[(t0g + tr) * 768 + c0 + cg] = hv;
    half2v lo, hi;
    lo[0] = hv[0]; lo[1] = hv[1]; hi[0] = hv[2]; hi[1] = hv[3];
    *(half2v*)&lt[tr * 66 + cg]     = lo;
    *(half2v*)&lt[tr * 66 + cg + 2] = hi;
  }
  __syncthreads();
  const int c = tid >> 2, tch = tid & 3;
  half8 o0, o1;
#pragma unroll
  for (int j = 0; j < 8; ++j) o0[j] = lt[(tch * 16 + j) * 66 + c];
#pragma unroll
  for (int j = 0; j < 8; ++j) o1[j] = lt[(tch * 16 + 8 + j) * 66 + c];
  _Float16* dst = xT + (long)b * 2408448 + (long)(c0 + c) * 3136 + tt * 64 + tch * 16;
  *(half8*)dst = o0;
  *(half8*)(dst + 8) = o1;
}

// ==================== Gram: G_b = xT_b . xT_b^T, symmetric 128^2 tiles ====================
__global__ __launch_bounds__(512)
void k_gram(const _Float16* __restrict__ xT, _Float16* __restrict__ G) {
  __shared__ _Float16 lds[2][2][128 * 64];   // 64 KiB
  const int tid = threadIdx.x;
  const int wv = tid >> 6, lane = tid & 63;
  const int g = lane >> 4, cidx = lane & 15;
  const int wr = wv >> 2, wc = wv & 3;

  const int nwg = (int)gridDim.x;
  const int q = nwg >> 3, r = nwg & 7;
  const int xcd = (int)blockIdx.x & 7, bidx = (int)blockIdx.x >> 3;
  int wg = (xcd < r ? xcd * (q + 1) : r * (q + 1) + (xcd - r) * q) + bidx;
  const int b = wg / 21;
  int p = wg % 21;
  int mt = 0;
  while (p >= 6 - mt) { p -= 6 - mt; ++mt; }
  const int nt = mt + p;

  const _Float16* Ab = xT + (long)b * 2408448 + (long)mt * 128 * 3136;
  const _Float16* Bb = xT + (long)b * 2408448 + (long)nt * 128 * 3136;

  const int srow8 = lane >> 3;
  const int sgr8  = (lane & 7) ^ srow8;

  auto stage = [&](int buf, int kt) {
#pragma unroll
    for (int l = 0; l < 2; ++l) {
      const int chunk = l * 8 + wv;
      const long grow = chunk * 8 + srow8;
      const long koff = (long)kt * 64 + sgr8 * 8;
      gload_lds16(Ab + grow * 3136 + koff, &lds[buf][0][chunk * 512]);
      gload_lds16(Bb + grow * 3136 + koff, &lds[buf][1][chunk * 512]);
    }
  };

  f32x4 acc[4][2] = {};
  stage(0, 0);
  __syncthreads();
  for (int kt = 0; kt < 49; ++kt) {
    const int cur = kt & 1;
    if (kt + 1 < 49) stage(cur ^ 1, kt + 1);
    half8 af[4][2], bf[2][2];
#pragma unroll
    for (int ks = 0; ks < 2; ++ks) {
      const int gran = (((ks << 2) + g) ^ (cidx & 7)) * 8;
#pragma unroll
      for (int m = 0; m < 4; ++m)
        af[m][ks] = *(const half8*)&lds[cur][0][(wr * 64 + m * 16 + cidx) * 64 + gran];
#pragma unroll
      for (int n = 0; n < 2; ++n)
        bf[n][ks] = *(const half8*)&lds[cur][1][(wc * 32 + n * 16 + cidx) * 64 + gran];
    }
#pragma unroll
    for (int ks = 0; ks < 2; ++ks)
#pragma unroll
      for (int m = 0; m < 4; ++m)
#pragma unroll
        for (int n = 0; n < 2; ++n)
          acc[m][n] = MFMA_F16(af[m][ks], bf[n][ks], acc[m][n]);
    __syncthreads();
  }
  _Float16* Gb = G + (long)b * 589824;
  const long m0 = (long)mt * 128, n0 = (long)nt * 128;
#pragma unroll
  for (int m = 0; m < 4; ++m)
#pragma unroll
    for (int rr = 0; rr < 4; ++rr) {
      const long row = m0 + wr * 64 + m * 16 + g * 4 + rr;
#pragma unroll
      for (int n = 0; n < 2; ++n)
        Gb[row * 768 + n0 + wc * 32 + n * 16 + cidx] = (_Float16)acc[m][n][rr];
    }
  if (mt != nt) {
#pragma unroll
    for (int m = 0; m < 4; ++m)
#pragma unroll
      for (int n = 0; n < 2; ++n) {
        half4 hv;
#pragma unroll
        for (int rr = 0; rr < 4; ++rr) hv[rr] = (_Float16)acc[m][n][rr];
        const long col  = n0 + wc * 32 + n * 16 + cidx;
        const long row0 = m0 + wr * 64 + m * 16 + g * 4;
        *(half4*)&Gb[col * 768 + row0] = hv;
      }
  }
}

#define XPH(CURA, CURB, MLO, NA, NBUF, NKS, NMLO, LOADB, NB, STAGE, BDRY)      \
  {                                                                            \
    STAGE;                                                                     \
    if (BDRY) {                                                                \
      asm volatile("s_waitcnt vmcnt(4)" ::: "memory");                         \
      __builtin_amdgcn_sched_barrier(0);                                       \
    }                                                                          \
    __builtin_amdgcn_s_barrier();                                              \
    _Pragma("unroll")                                                          \
    for (int mm = 0; mm < 4; ++mm)                                             \
      NA[mm] = *(const half8*)&lds[(NBUF)*32768 + (NKS)*8192 + raA + ((NMLO)+mm)*512]; \
    if (LOADB) {                                                               \
      _Pragma("unroll")                                                        \
      for (int nn = 0; nn < 4; ++nn)                                           \
        NB[nn] = *(const half8*)&lds[(NBUF)*32768 + (NKS)*8192 + raB + nn*512]; \
    }                                                                          \
    __builtin_amdgcn_sched_barrier(0);                                         \
    __builtin_amdgcn_s_setprio(1);                                             \
    _Pragma("unroll")                                                          \
    for (int mm = 0; mm < 4; ++mm)                                             \
      _Pragma("unroll")                                                        \
      for (int nn = 0; nn < 4; ++nn)                                           \
        acc[(MLO)+mm][nn] = MFMA_F16(CURA[mm], CURB[nn], acc[(MLO)+mm][nn]);   \
    __builtin_amdgcn_s_setprio(0);                                             \
    __builtin_amdgcn_s_barrier();                                              \
  }

// ==================== 256x256 8-phase bt-GEMM (wfin) ====================
template<bool OUT_F32>
__global__ __launch_bounds__(512, 2)
void k_gemm8p(const _Float16* __restrict__ A, const _Float16* __restrict__ B,
              void* __restrict__ Cv, const float* __restrict__ bias,
              int Mt, int Nt, long Areal, long Astr, long Bstr, long Cstr,
              long N, long K)
{
  __shared__ _Float16 lds[65536];  // 128 KiB
  const int tid  = threadIdx.x;
  const int wv   = tid >> 6, lane = tid & 63;
  const int g    = lane >> 4, cidx = lane & 15;
  const int wr   = wv >> 2, wc = wv & 3;

  const int nwg = (int)gridDim.x;
  const int q = nwg >> 3, r = nwg & 7;
  const int xcd = (int)blockIdx.x & 7, bidx = (int)blockIdx.x >> 3;
  int wg = (xcd < r ? xcd * (q + 1) : r * (q + 1) + (xcd - r) * q) + bidx;

  const int tpb = Mt * Nt;
  const int b   = wg / tpb;
  const int rem = wg - b * tpb;
  const long mt = rem % Mt, nt = rem / Mt;
  const long m0 = mt * 256, n0 = nt * 256;

  const int NT = (int)(K >> 6);
  const int NI = NT >> 1;

  const _Float16* Ab = A + b * Astr + m0 * K;
  const _Float16* Bb = B + b * Bstr + n0 * K;

  const int srow = lane >> 2;
  const int sgr  = (lane & 3) ^ ((lane >> 3) & 3);

  auto stage = [&](int op, int buf, int kh, int t) {
    const _Float16* src = op ? Bb : Ab;
    const long koff = (long)t * 64 + kh * 32 + sgr * 8;
#pragma unroll
    for (int l = 0; l < 2; ++l) {
      const int chunk = l * 8 + wv;
      gload_lds16(src + (long)(chunk * 16 + srow) * K + koff,
                  &lds[buf * 32768 + op * 16384 + kh * 8192 + chunk * 512]);
    }
  };

  const int gr  = (g ^ ((cidx >> 1) & 3)) * 8;
  const int raA = (wr * 128 + cidx) * 32 + gr;
  const int raB = 16384 + (wc * 64 + cidx) * 32 + gr;

  f32x4 acc[8][4] = {};

  stage(0, 0, 0, 0); stage(1, 0, 0, 0);
  stage(0, 0, 1, 0); stage(1, 0, 1, 0);
  stage(0, 1, 0, 1); stage(1, 1, 0, 1);
  asm volatile("s_waitcnt vmcnt(4)" ::: "memory");
  __builtin_amdgcn_sched_barrier(0);
  __builtin_amdgcn_s_barrier();

  half8 afA[4], afB[4], bfA[4], bfB[4];
#pragma unroll
  for (int mm = 0; mm < 4; ++mm) afA[mm] = *(const half8*)&lds[raA + mm * 512];
#pragma unroll
  for (int nn = 0; nn < 4; ++nn) bfA[nn] = *(const half8*)&lds[raB + nn * 512];

  for (int it = 0; it < NI; ++it) {
    const int t1c = 2 * it + 1;
    int tn2 = 2 * it + 2; if (tn2 >= NT) tn2 -= NT;
    int tn3 = 2 * it + 3; if (tn3 >= NT) tn3 -= NT;
    XPH(afA, bfA, 0, afB, 0, 0, 4, 0, bfB, stage(0, 1, 1, t1c), false)
    XPH(afB, bfA, 4, afA, 0, 1, 0, 1, bfB, stage(1, 1, 1, t1c), false)
    XPH(afA, bfB, 0, afB, 0, 1, 4, 0, bfA, stage(0, 0, 0, tn2), false)
    XPH(afB, bfB, 4, afA, 1, 0, 0, 1, bfA, stage(1, 0, 0, tn2), true )
    XPH(afA, bfA, 0, afB, 1, 0, 4, 0, bfB, stage(0, 0, 1, tn2), false)
    XPH(afB, bfA, 4, afA, 1, 1, 0, 1, bfB, stage(1, 0, 1, tn2), false)
    XPH(afA, bfB, 0, afB, 1, 1, 4, 0, bfA, stage(0, 1, 0, tn3), false)
    XPH(afB, bfB, 4, afA, 0, 0, 0, 1, bfA, stage(1, 1, 0, tn3), true )
  }

  float bv[4] = {0.f, 0.f, 0.f, 0.f};
  if (bias) {
#pragma unroll
    for (int n = 0; n < 4; ++n) bv[n] = bias[n0 + wc * 64 + n * 16 + cidx];
  }
  if constexpr (OUT_F32) {
    float* C = (float*)Cv + b * Cstr;
#pragma unroll
    for (int m = 0; m < 8; ++m)
#pragma unroll
      for (int rr = 0; rr < 4; ++rr) {
        const long row = m0 + wr * 128 + m * 16 + g * 4 + rr;
        if (row < Areal) {
#pragma unroll
          for (int n = 0; n < 4; ++n)
            C[row * N + (n0 + wc * 64 + n * 16 + cidx)] = acc[m][n][rr] + bv[n];
        }
      }
  } else {
    _Float16* C = (_Float16*)Cv + b * Cstr;
#pragma unroll
    for (int m = 0; m < 8; ++m)
#pragma unroll
      for (int rr = 0; rr < 4; ++rr) {
        const long row = m0 + wr * 128 + m * 16 + g * 4 + rr;
        if (row < Areal) {
#pragma unroll
          for (int n = 0; n < 4; ++n)
            C[row * N + (n0 + wc * 64 + n * 16 + cidx)] = (_Float16)acc[m][n][rr];
        }
      }
  }
}

// ==================== k_g2t: 128x256 bt-GEMM, 3-deep A-ring / 2-deep B-ring (QG) ====================
#define XP2(CURA, CURB, NA, NSA, NB, NSB, NKS, STAGE, BDRY)                    \
  {                                                                            \
    STAGE;                                                                     \
    if (BDRY) {                                                                \
      asm volatile("s_waitcnt vmcnt(2)" ::: "memory");                         \
      __builtin_amdgcn_sched_barrier(0);                                       \
    }                                                                          \
    __builtin_amdgcn_s_barrier();                                              \
    _Pragma("unroll")                                                          \
    for (int mm = 0; mm < 4; ++mm)                                             \
      NA[mm] = *(const half8*)&lds[(NSA)*8192 + ((raA + mm*1024) ^ ((NKS)*32))]; \
    _Pragma("unroll")                                                          \
    for (int nn = 0; nn < 4; ++nn)                                             \
      NB[nn] = *(const half8*)&lds[24576 + (NSB)*16384 + ((raB + nn*1024) ^ ((NKS)*32))]; \
    __builtin_amdgcn_sched_barrier(0);                                         \
    __builtin_amdgcn_s_setprio(1);                                             \
    _Pragma("unroll")                                                          \
    for (int mm = 0; mm < 4; ++mm)                                             \
      _Pragma("unroll")                                                        \
      for (int nn = 0; nn < 4; ++nn)                                           \
        acc[mm][nn] = MFMA_F16(CURA[mm], CURB[nn], acc[mm][nn]);               \
    __builtin_amdgcn_s_setprio(0);                                             \
    __builtin_amdgcn_s_barrier();                                              \
  }

template<bool OUT_F32>
__global__ __launch_bounds__(512, 1)
void k_g2t(const _Float16* __restrict__ A, const _Float16* __restrict__ B,
           void* __restrict__ Cv, const float* __restrict__ bias,
           int Mt, int Nt, long Areal, long Astr, long Bstr, long Cstr, long N)
{
  __shared__ _Float16 lds[57344];  // 112 KiB
  const int tid = threadIdx.x;
  const int wv = tid >> 6, lane = tid & 63;
  const int g = lane >> 4, cidx = lane & 15;
  const int wr = wv >> 2, wc = wv & 3;
  const long K = 768;

  const int nwg = (int)gridDim.x;
  const int q = nwg >> 3, r = nwg & 7;
  const int xcd = (int)blockIdx.x & 7, bidx = (int)blockIdx.x >> 3;
  int wg = (xcd < r ? xcd * (q + 1) : r * (q + 1) + (xcd - r) * q) + bidx;
  const int tpb = Mt * Nt;
  const int b = wg / tpb;
  const int rem = wg - b * tpb;
  const long mt = rem % Mt, nt = rem / Mt;
  const long m0 = mt * 128, n0 = nt * 256;

  const _Float16* Ab = A + b * Astr + m0 * K;
  const _Float16* Bb = B + b * Bstr + n0 * K;

  const int srow8 = lane >> 3;
  const int sgr8  = (lane & 7) ^ srow8;

  auto stageA = [&](int slot, int t) {
#pragma unroll
    for (int l = 0; l < 2; ++l) {
      const int chunk = l * 8 + wv;
      gload_lds16(Ab + (long)(chunk * 8 + srow8) * K + (long)t * 64 + sgr8 * 8,
                  &lds[slot * 8192 + chunk * 512]);
    }
  };
  auto stageB = [&](int slot, int t) {
#pragma unroll
    for (int l = 0; l < 4; ++l) {
      const int chunk = l * 8 + wv;
      gload_lds16(Bb + (long)(chunk * 8 + srow8) * K + (long)t * 64 + sgr8 * 8,
                  &lds[24576 + slot * 16384 + chunk * 512]);
    }
  };

  const int gr0 = (g ^ (cidx & 7)) * 8;
  const int raA = (wr * 64 + cidx) * 64 + gr0;
  const int raB = (wc * 64 + cidx) * 64 + gr0;

  f32x4 acc[4][4] = {};

  stageA(0, 0);
  stageB(0, 0);
  stageA(1, 1);
  asm volatile("s_waitcnt vmcnt(2)" ::: "memory");
  __builtin_amdgcn_sched_barrier(0);
  __builtin_amdgcn_s_barrier();

  half8 afA[4], afB[4], bfA[4], bfB[4];
#pragma unroll
  for (int mm = 0; mm < 4; ++mm) afA[mm] = *(const half8*)&lds[raA + mm * 1024];
#pragma unroll
  for (int nn = 0; nn < 4; ++nn) bfA[nn] = *(const half8*)&lds[24576 + raB + nn * 1024];

  int sa = 0, sb = 0;
  for (int t = 0; t < 12; ++t) {
    const int san  = (sa == 2) ? 0 : sa + 1;
    const int sap2 = (san == 2) ? 0 : san + 1;
    const int sbn  = sb ^ 1;
    int tb1 = t + 1; if (tb1 >= 12) tb1 -= 12;
    int tb2 = t + 2; if (tb2 >= 12) tb2 -= 12;
    XP2(afA, bfA, afB, sa, bfB, sb, 1, stageB(sbn, tb1), false)
    XP2(afB, bfB, afA, san, bfA, sbn, 0, stageA(sap2, tb2), true)
    sa = san; sb = sbn;
  }

  float bv[4] = {0.f, 0.f, 0.f, 0.f};
  if (bias) {
#pragma unroll
    for (int n = 0; n < 4; ++n) bv[n] = bias[n0 + wc * 64 + n * 16 + cidx];
  }
  if constexpr (OUT_F32) {
    float* C = (float*)Cv + b * Cstr;
#pragma unroll
    for (int m = 0; m < 4; ++m)
#pragma unroll
      for (int rr = 0; rr < 4; ++rr) {
        const long row = m0 + wr * 64 + m * 16 + g * 4 + rr;
        if (row < Areal) {
#pragma unroll
          for (int n = 0; n < 4; ++n)
            C[row * N + (n0 + wc * 64 + n * 16 + cidx)] = acc[m][n][rr] + bv[n];
        }
      }
  } else {
    _Float16* C = (_Float16*)Cv + b * Cstr;
#pragma unroll
    for (int m = 0; m < 4; ++m)
#pragma unroll
      for (int rr = 0; rr < 4; ++rr) {
        const long row = m0 + wr * 64 + m * 16 + g * 4 + rr;
        if (row < Areal) {
#pragma unroll
          for (int n = 0; n < 4; ++n)
            C[row * N + (n0 + wc * 64 + n * 16 + cidx)] = (_Float16)acc[m][n][rr];
        }
      }
  }
}

// ==================== final: out = x16 . wfin^T + bias, asymmetric-depth pipeline ====================
#define XP3(CURA, CURB, MLO, NA, NSA, NKS, NMLO, LOADB, NB, NSB, STAGE, BDRY)  \
  {                                                                            \
    STAGE;                                                                     \
    if (BDRY) {                                                                \
      asm volatile("s_waitcnt vmcnt(4)" ::: "memory");                         \
      __builtin_amdgcn_sched_barrier(0);                                       \
    }                                                                          \
    __builtin_amdgcn_s_barrier();                                              \
    _Pragma("unroll")                                                          \
    for (int mm = 0; mm < 4; ++mm)                                             \
      NA[mm] = *(const half8*)&lds[(NSA)*16384 + ((raA + ((NMLO)+mm)*1024) ^ ((NKS)*32))]; \
    if (LOADB) {                                                               \
      _Pragma("unroll")                                                        \
      for (int nn = 0; nn < 4; ++nn)                                           \
        NB[nn] = *(const half8*)&lds[49152 + (NSB)*16384 + ((raB + nn*1024) ^ ((NKS)*32))]; \
    }                                                                          \
    __builtin_amdgcn_sched_barrier(0);                                         \
    __builtin_amdgcn_s_setprio(1);                                             \
    _Pragma("unroll")                                                          \
    for (int mm = 0; mm < 4; ++mm)                                             \
      _Pragma("unroll")                                                        \
      for (int nn = 0; nn < 4; ++nn)                                           \
        acc[(MLO)+mm][nn] = MFMA_F16(CURA[mm], CURB[nn], acc[(MLO)+mm][nn]);   \
    __builtin_amdgcn_s_setprio(0);                                             \
    __builtin_amdgcn_s_barrier();                                              \
  }

__global__ __launch_bounds__(512, 1)
void k_final3(const _Float16* __restrict__ A, const _Float16* __restrict__ B,
              float* __restrict__ C, const float* __restrict__ bias)
{
  __shared__ _Float16 lds[81920];  // 160 KiB: A 3x16384 @0, B 2x16384 @49152
  const int tid = threadIdx.x;
  const int wv = tid >> 6, lane = tid & 63;
  const int g = lane >> 4, cidx = lane & 15;
  const int wr = wv >> 2, wc = wv & 3;
  const long K = 768;

  const int nwg = (int)gridDim.x;   // 624
  const int q = nwg >> 3, r = nwg & 7;
  const int xcd = (int)blockIdx.x & 7, bidx = (int)blockIdx.x >> 3;
  int wg = (xcd < r ? xcd * (q + 1) : r * (q + 1) + (xcd - r) * q) + bidx;
  const int b = wg / 39;
  const int rem = wg - b * 39;
  const long mt = rem % 13, nt = rem / 13;
  const long m0 = mt * 256, n0 = nt * 256;

  const _Float16* Ab = A + (long)b * 2408448 + m0 * K;
  const _Float16* Bb = B + (long)b * 589824 + n0 * K;

  const int srow8 = lane >> 3;
  const int sgr8  = (lane & 7) ^ srow8;

  auto stageA = [&](int slot, int t, int part) {
#pragma unroll
    for (int l = part * 2; l < part * 2 + 2; ++l) {
      const int chunk = l * 8 + wv;
      gload_lds16(Ab + (long)(chunk * 8 + srow8) * K + (long)t * 64 + sgr8 * 8,
                  &lds[slot * 16384 + chunk * 512]);
    }
  };
  auto stageB = [&](int slot, int t, int part) {
#pragma unroll
    for (int l = part * 2; l < part * 2 + 2; ++l) {
      const int chunk = l * 8 + wv;
      gload_lds16(Bb + (long)(chunk * 8 + srow8) * K + (long)t * 64 + sgr8 * 8,
                  &lds[49152 + slot * 16384 + chunk * 512]);
    }
  };

  const int gr0 = (g ^ (cidx & 7)) * 8;
  const int raA = (wr * 128 + cidx) * 64 + gr0;
  const int raB = (wc * 64 + cidx) * 64 + gr0;

  f32x4 acc[8][4] = {};

  stageA(0, 0, 0); stageA(0, 0, 1);
  stageB(0, 0, 0); stageB(0, 0, 1);
  stageA(1, 1, 0); stageA(1, 1, 1);
  asm volatile("s_waitcnt vmcnt(4)" ::: "memory");
  __builtin_amdgcn_sched_barrier(0);
  __builtin_amdgcn_s_barrier();

  half8 afA[4], afB[4], bfA[4], bfB[4];
#pragma unroll
  for (int mm = 0; mm < 4; ++mm)
    afA[mm] = *(const half8*)&lds[raA + mm * 1024];
#pragma unroll
  for (int nn = 0; nn < 4; ++nn)
    bfA[nn] = *(const half8*)&lds[49152 + raB + nn * 1024];

  int sa = 0, sb = 0;
  for (int t = 0; t < 12; ++t) {
    const int san  = (sa == 2) ? 0 : sa + 1;
    const int sap2 = (san == 2) ? 0 : san + 1;
    const int sbn  = sb ^ 1;
    int tb1 = t + 1; if (tb1 >= 12) tb1 -= 12;
    int tb2 = t + 2; if (tb2 >= 12) tb2 -= 12;
    XP3(afA, bfA, 0, afB, sa, 0, 4, 0, bfB, 0, stageB(sbn, tb1, 0), false)
    XP3(afB, bfA, 4, afA, sa, 1, 0, 1, bfB, sb, stageB(sbn, tb1, 1), false)
    XP3(afA, bfB, 0, afB, sa, 1, 4, 0, bfA, 0, stageA(sap2, tb2, 0), false)
    XP3(afB, bfB, 4, afA, san, 0, 0, 1, bfA, sbn, stageA(sap2, tb2, 1), true)
    sa = san; sb = sbn;
  }

  float bv[4];
#pragma unroll
  for (int n = 0; n < 4; ++n) bv[n] = bias[n0 + wc * 64 + n * 16 + cidx];
  float* Cb = C + (long)b * 2408448;
#pragma unroll
  for (int m = 0; m < 8; ++m)
#pragma unroll
    for (int rr = 0; rr < 4; ++rr) {
      const long row = m0 + wr * 128 + m * 16 + g * 4 + rr;
      if (row < 3136) {
#pragma unroll
        for (int n = 0; n < 4; ++n)
          Cb[row * 768 + (n0 + wc * 64 + n * 16 + cidx)] = acc[m][n][rr] + bv[n];
      }
    }
}

// ==================== heads: S/norms from QG, softmax, WeffT. One block per (b,h) ====================
__global__ __launch_bounds__(256)
void k_heads(const _Float16* __restrict__ QG, const _Float16* __restrict__ w16,
             const _Float16* __restrict__ wvT, const float* __restrict__ temperature,
             _Float16* __restrict__ weffT)
{
  const int b = blockIdx.x >> 4, h = blockIdx.x & 15;
  const int tid = threadIdx.x;
  const int w = tid >> 6, lane = tid & 63;
  const int g = lane >> 4, c = lane & 15;

  __shared__ float red[4][48 * 48];
  __shared__ float redss[4][2][48];
  __shared__ float inv[2][48];
  __shared__ _Float16 Pb[48 * 64];

  const _Float16* QGq = QG + (long)b * 1179648 + (long)(h * 48) * 768;
  const _Float16* QGk = QGq + 768L * 768;
  const _Float16* Wq  = w16 + (long)(h * 48) * 768;
  const _Float16* Wk  = w16 + (long)(768 + h * 48) * 768;

  f32x4 aS[3][3] = {};
  f32x4 aq[3] = {};
  f32x4 ak[3] = {};
  for (int ks = w * 6; ks < w * 6 + 6; ++ks) {
    const int k0 = ks * 32 + g * 8;
    half8 t1[3], t3[3], wqf[3], wkf[3];
#pragma unroll
    for (int m = 0; m < 3; ++m) {
      const long ro = (long)(m * 16 + c) * 768 + k0;
      t1[m]  = *(const half8*)(QGq + ro);
      t3[m]  = *(const half8*)(QGk + ro);
      wqf[m] = *(const half8*)(Wq + ro);
      wkf[m] = *(const half8*)(Wk + ro);
    }
#pragma unroll
    for (int m = 0; m < 3; ++m) {
      aq[m] = MFMA_F16(t1[m], wqf[m], aq[m]);
      ak[m] = MFMA_F16(t3[m], wkf[m], ak[m]);
#pragma unroll
      for (int n = 0; n < 3; ++n)
        aS[m][n] = MFMA_F16(t1[m], wkf[n], aS[m][n]);
    }
  }

#pragma unroll
  for (int m = 0; m < 3; ++m) {
#pragma unroll
    for (int n = 0; n < 3; ++n)
#pragma unroll
      for (int rr = 0; rr < 4; ++rr)
        red[w][(m * 16 + g * 4 + rr) * 48 + n * 16 + c] = aS[m][n][rr];
#pragma unroll
    for (int rr = 0; rr < 4; ++rr)
      if (c == g * 4 + rr) {
        redss[w][0][m * 16 + c] = aq[m][rr];
        redss[w][1][m * 16 + c] = ak[m][rr];
      }
  }
  __syncthreads();

  if (tid < 96) {
    const int is_k = tid / 48, d = tid % 48;
    const float s = redss[0][is_k][d] + redss[1][is_k][d] + redss[2][is_k][d] + redss[3][is_k][d];
    inv[is_k][d] = 1.0f / fmaxf(sqrtf(s), 1e-12f);
  }
  __syncthreads();

  if (tid < 48) {
    const int d = tid;
    const float iq = inv[0][d] * temperature[h];
    float rowv[48];
    float mx = -3.0e38f;
#pragma unroll
    for (int e = 0; e < 48; ++e) {
      const int idx = d * 48 + e;
      float t = (red[0][idx] + red[1][idx] + red[2][idx] + red[3][idx]) * iq * inv[1][e];
      rowv[e] = t;
      mx = fmaxf(mx, t);
    }
    float sum = 0.f;
#pragma unroll
    for (int e = 0; e < 48; ++e) {
      const float pv = __expf(rowv[e] - mx);
      rowv[e] = pv;
      sum += pv;
    }
    const float is = 1.0f / sum;
#pragma unroll
    for (int e = 0; e < 48; ++e)
      Pb[d * 64 + e] = (_Float16)(rowv[e] * is);
#pragma unroll
    for (int e = 48; e < 64; ++e)
      Pb[d * 64 + e] = (_Float16)0.f;
  }
  __syncthreads();

  half8 pf[3][2];
#pragma unroll
  for (int nf = 0; nf < 3; ++nf)
#pragma unroll
    for (int ks = 0; ks < 2; ++ks)
      pf[nf][ks] = *(const half8*)&Pb[(nf * 16 + c) * 64 + ks * 32 + g * 8];

  const _Float16* wvh = wvT + (long)h * 768 * 64;
  _Float16* wout = weffT + (long)b * 589824 + h * 48;

  for (int m = 0; m < 12; ++m) {
    const int f0 = w * 192 + m * 16;
    half8 va[2];
#pragma unroll
    for (int ks = 0; ks < 2; ++ks)
      va[ks] = *(const half8*)&wvh[(long)(f0 + c) * 64 + ks * 32 + g * 8];
    f32x4 a3[3] = {};
#pragma unroll
    for (int ks = 0; ks < 2; ++ks)
#pragma unroll
      for (int nf = 0; nf < 3; ++nf)
        a3[nf] = MFMA_F16(va[ks], pf[nf][ks], a3[nf]);
#pragma unroll
    for (int nf = 0; nf < 3; ++nf)
#pragma unroll
      for (int rr = 0; rr < 4; ++rr)
        wout[(long)(f0 + g * 4 + rr) * 768 + nf * 16 + c] = (_Float16)a3[nf][rr];
  }
}

// -------------------- launch --------------------
extern "C" void kernel_launch(void* const* d_in, const int* in_sizes, int n_in,
                              void* d_out, int out_size, void* d_ws, size_t ws_size,
                              hipStream_t stream)
{
  (void)in_sizes; (void)n_in; (void)out_size; (void)ws_size;
  const float* x      = (const float*)d_in[0];
  const float* w_qkv  = (const float*)d_in[1];
  const float* temp   = (const float*)d_in[2];
  const float* w_proj = (const float*)d_in[3];
  const float* b_proj = (const float*)d_in[4];
  float* out = (float*)d_out;

  char* ws = (char*)d_ws;
  _Float16* x16   = (_Float16*)(ws);
  _Float16* xT    = (_Float16*)(ws + 77070336L);
  _Float16* G     = (_Float16*)(ws + 154140672L);
  _Float16* QG    = (_Float16*)(ws + 173015040L);
  _Float16* weffT = (_Float16*)(ws + 210763776L);
  _Float16* wfin  = (_Float16*)(ws + 229638144L);
  _Float16* w16   = (_Float16*)(ws + 248512512L);
  _Float16* wp16  = (_Float16*)(ws + 252051456L);
  _Float16* wvT   = (_Float16*)(ws + 253231104L);

  // x convert + transpose (blocks 0..9407) and weight converts (blocks 9408..9919)
  k_cvtx<<<9920, 256, 0, stream>>>(x, x16, xT, w_qkv, w_proj, w16, wp16, wvT);
  // G_b = xT_b . xT_b^T (symmetric), 8-wave BK=64
  k_gram<<<336, 512, 0, stream>>>(xT, G);
  // QG_b = w16[0:1536] . G_b  (128x256 deep-pipeline: 576 blocks)
  k_g2t<false><<<576, 512, 0, stream>>>(w16, G, QG, nullptr,
                                        12, 3, 1536, 0, 589824, 1179648, 768);
  // per (b,h): S, norms, softmax, WeffT
  k_heads<<<256, 256, 0, stream>>>(QG, w16, wvT, temp, weffT);
  // wfin_b = Wp . Weff_b  (8-phase 256^2, 144 blocks)
  k_gemm8p<false><<<144, 512, 0, stream>>>(wp16, weffT, wfin, nullptr,
                                           3, 3, 768, 0, 589824, 589824, 768, 768);
  // final: out_b = x16_b . wfin_b^T + bias  (asymmetric-depth 160KiB pipeline, R13-best)
  k_final3<<<624, 512, 0, stream>>>(x16, wfin, out, b_proj);
}